// Round 8
// baseline (403.439 us; speedup 1.0000x reference)
//
#include <hip/hip_runtime.h>
#include <stdint.h>

typedef uint16_t u16;
typedef _Float16 f16;
typedef __attribute__((ext_vector_type(8)))  f16      f16x8;
typedef __attribute__((ext_vector_type(2)))  __fp16   h16x2;   // native type of cvt_pkrtz
typedef __attribute__((ext_vector_type(8)))  uint16_t u16x8;
typedef __attribute__((ext_vector_type(4)))  uint16_t u16x4;
typedef __attribute__((ext_vector_type(2)))  uint32_t u32x2;
typedef __attribute__((ext_vector_type(4)))  float    f32x4;

#define LOG2E 1.44269504088896340736f
#define MFMA16F(a, b, c) __builtin_amdgcn_mfma_f32_16x16x32_f16((a), (b), (c), 0, 0, 0)

__device__ __forceinline__ u16 f2h(float f) {   // fp32 -> f16 RNE
  f16 h = (f16)f;
  return __builtin_bit_cast(u16, h);
}
__device__ __forceinline__ uint32_t pk2(float a, float b) {  // packed f32->f16 RTZ
  h16x2 h = __builtin_amdgcn_cvt_pkrtz(a, b);
  return __builtin_bit_cast(uint32_t, h);
}

// LDS tiles: [rows][64 f16] = 8 chunks of 16B per row, chunk XOR-swizzled by row&7.
__device__ __forceinline__ f16x8 ldsFrag(const u16* base, int row, int chunk) {
  const u16* p = base + row * 64 + ((chunk ^ (row & 7)) << 3);
  u16x8 raw = *(const u16x8*)p;
  return __builtin_bit_cast(f16x8, raw);
}
__device__ __forceinline__ void ldsPut(u16* base, int row, int logicalChunk, u16x8 v) {
  u16* p = base + row * 64 + ((logicalChunk ^ (row & 7)) << 3);
  *(u16x8*)p = v;
}

// ---------------- kernel 0: pack weights ----------------
// Wt[n][k] f16 (n<64: Wf*log2e, n<128: Wg, else Wh), biasc[n] fp32 (bf*log2e).
__global__ __launch_bounds__(256) void pack_weights2(
    const float* __restrict__ Wf, const float* __restrict__ Wg,
    const float* __restrict__ Wh, const float* __restrict__ bfv,
    const float* __restrict__ bgv, const float* __restrict__ bhv,
    u16* __restrict__ Wt, float* __restrict__ biasc) {
  __shared__ u16 T[64 * 64];       // [k][n]
  const int nt = blockIdx.x >> 3;  // 0..9
  const int kt = blockIdx.x & 7;   // 0..7
  const int n0 = nt * 64, k0 = kt * 64;
  const float* src; int stride, cbase; float scale = 1.0f;
  if (nt == 0)      { src = Wf; stride = 64;  cbase = 0;        scale = LOG2E; }
  else if (nt == 1) { src = Wg; stride = 64;  cbase = 0; }
  else              { src = Wh; stride = 512; cbase = n0 - 128; }
  const int t = threadIdx.x;
  const int cl = (t & 15) * 4, r0 = t >> 4;
#pragma unroll
  for (int j = 0; j < 4; ++j) {
    int r = r0 + j * 16;
    f32x4 v = *(const f32x4*)(src + (size_t)(k0 + r) * stride + cbase + cl);
    u16x4 o;
#pragma unroll
    for (int i = 0; i < 4; ++i) o[i] = f2h(v[i] * scale);
    *(u16x4*)(T + r * 64 + cl) = o;
  }
  __syncthreads();
  const int n = t >> 2, kq = (t & 3) * 16;
  u16x8 a, b2;
#pragma unroll
  for (int i = 0; i < 8; ++i) { a[i] = T[(kq + i) * 64 + n]; b2[i] = T[(kq + 8 + i) * 64 + n]; }
  *(u16x8*)(Wt + (size_t)(n0 + n) * 512 + k0 + kq) = a;
  *(u16x8*)(Wt + (size_t)(n0 + n) * 512 + k0 + kq + 8) = b2;
  if (kt == 0 && t < 64) {
    float bv = (nt == 0) ? bfv[t] * LOG2E : (nt == 1) ? bgv[t] : bhv[cbase + t];
    biasc[n0 + t] = bv;
  }
}

// ---------------- kernel 1: projection GEMM v4 — x read ONCE ----------------
// 256 blocks x 512 thr (8 waves). Block: M=64 rows x N=640 (ALL outputs).
// A (x tile) staged fp32->f16 into LDS dbuf; B (Wt, 640 KB, L2-resident) read
// DIRECT from L2. Wave w owns n in [w*80, w*80+80) (5 tiles of 16).
// h epilogue: LDS transpose (64 KB) -> coalesced ht stores.
__global__ __launch_bounds__(512, 2) void proj_gemm4(
    const float* __restrict__ x, const u16* __restrict__ Wt,
    const float* __restrict__ biasc,
    u16* __restrict__ fo, u16* __restrict__ go, u16* __restrict__ ht) {
  __shared__ u16 lds_a[2 * 64 * 64];   // 16 KB A dbuf
  __shared__ u16 T[512 * 64];          // 64 KB transpose buffer
  const int t = threadIdx.x, lane = t & 63, w = t >> 6;
  const int m0 = blockIdx.x * 64;
  const int l15 = lane & 15, l4 = lane >> 4;
  const int arow = t >> 3, achk = t & 7;     // A staging: row, chunk

  f32x4 acc[4][5];
#pragma unroll
  for (int i = 0; i < 4; ++i)
#pragma unroll
    for (int j = 0; j < 5; ++j) acc[i][j] = (f32x4)(0.f);

  auto stage_a = [&](int kb) {   // x[m0+arow][kb*64 + achk*8 ..+8] -> f16 LDS
    const float* s = x + (size_t)(m0 + arow) * 512 + kb * 64 + achk * 8;
    f32x4 a0 = *(const f32x4*)s;
    f32x4 a1 = *(const f32x4*)(s + 4);
    u16x8 v;
#pragma unroll
    for (int i = 0; i < 4; ++i) { v[i] = f2h(a0[i]); v[4 + i] = f2h(a1[i]); }
    ldsPut(lds_a + (kb & 1) * 64 * 64, arow, achk, v);
  };

  stage_a(0);
  __syncthreads();

  for (int kb = 0; kb < 8; ++kb) {
    const u16* abuf = lds_a + (kb & 1) * 64 * 64;
    // B frags direct from L2 (issue early)
    f16x8 bq[2][5];
#pragma unroll
    for (int ks = 0; ks < 2; ++ks)
#pragma unroll
      for (int nt = 0; nt < 5; ++nt) {
        const u16* bp = Wt + (size_t)(w * 80 + nt * 16 + l15) * 512 + kb * 64 + ks * 32 + l4 * 8;
        bq[ks][nt] = __builtin_bit_cast(f16x8, *(const u16x8*)bp);
      }
    if (kb < 7) stage_a(kb + 1);
#pragma unroll
    for (int ks = 0; ks < 2; ++ks) {
      f16x8 af[4];
#pragma unroll
      for (int mt = 0; mt < 4; ++mt) af[mt] = ldsFrag(abuf, mt * 16 + l15, ks * 4 + l4);
#pragma unroll
      for (int mt = 0; mt < 4; ++mt)
#pragma unroll
        for (int nt = 0; nt < 5; ++nt) acc[mt][nt] = MFMA16F(af[mt], bq[ks][nt], acc[mt][nt]);
    }
    __syncthreads();   // readers done with abuf; stage(kb+1) writes visible next iter
  }

  // ---- epilogue ----
#pragma unroll
  for (int nt = 0; nt < 5; ++nt) {
    int n = w * 80 + nt * 16 + l15;    // tile-uniform class (16-aligned boundaries)
    float bv = biasc[n];
#pragma unroll
    for (int mt = 0; mt < 4; ++mt) {
      int mb = mt * 16 + (l4 << 2);
      f32x4 a = acc[mt][nt];
      u16x4 v;
#pragma unroll
      for (int r = 0; r < 4; ++r) v[r] = f2h(a[r] + bv);
      if (n < 64) {
#pragma unroll
        for (int r = 0; r < 4; ++r) fo[(size_t)(m0 + mb + r) * 64 + n] = v[r];
      } else if (n < 128) {
#pragma unroll
        for (int r = 0; r < 4; ++r) go[(size_t)(m0 + mb + r) * 64 + (n - 64)] = v[r];
      } else {
        int nl = n - 128;              // 0..511
        u16* dst = T + nl * 64 + (((mb >> 3) ^ (nl & 7)) << 3) + (mb & 7);
        *(u16x4*)dst = v;
      }
    }
  }
  __syncthreads();
  // coalesced ht stores: thread t -> vcol (t>>3), chunk (t&7); 8 rounds
  const int bb = m0 >> 12, posb = m0 & 4095;
  const int vrow = t >> 3, vchk = t & 7;
#pragma unroll
  for (int j = 0; j < 8; ++j) {
    int vcol = j * 64 + vrow;
    u16x8 v = *(const u16x8*)(T + vcol * 64 + ((vchk ^ (vcol & 7)) << 3));
    *(u16x8*)(ht + ((size_t)(bb * 512 + vcol) << 12) + posb + vchk * 8) = v;
  }
}

// ---------------- kernel 2: attention v7 — 4 blocks/CU pipelined ----------
// 1024 blocks x 4 waves (4/CU, 4 waves/SIMD). Block: Q=32 q x VC=256 c,
// Kt=64 keys/iter; slice i&7 -> (batch, c-half): 2MB ht slice per XCD.
// Same pipeline as attn6: S(k+1) -> PV(k) -> prefetch -> exp(k+1)+P-write
// -> barrier. Halved per-wave VALU (8 exp), 4x waves for latency hiding.
__global__ __launch_bounds__(256, 4) void attn7(
    const f16* __restrict__ fq, const f16* __restrict__ gk,
    const f16* __restrict__ ht, const float* __restrict__ x,
    const float* __restrict__ gamma_p, float* __restrict__ out) {
  __shared__ u16 lds_p[2][32 * 64];    // P dbuf, swizzled [q][key]
  __shared__ float lds_red[4 * 32];
  __shared__ float lds_linv[32];

  const int i = blockIdx.x;            // 1024 blocks
  const int slice = i & 7;             // XCD-aligned
  const int b = slice >> 1, vq = slice & 1;
  const int qb = i >> 3;               // 0..127
  const int q0 = qb * 32, vc0 = vq * 256;

  const int t = threadIdx.x, lane = t & 63, w = t >> 6;
  const int l15 = lane & 15, l4 = lane >> 4;
  const float gamma = gamma_p[0];

  const f16* gkb = gk + ((size_t)(b * 4096) + w * 16 + l15) * 64 + l4 * 8;
  const f16* htw = ht + ((size_t)(b * 512 + vc0 + w * 64 + l15)) * 4096 + l4 * 8;

  // f B-frags (S^T): all 32 q of this block, pinned
  f16x8 fB[2][2];
#pragma unroll
  for (int qt = 0; qt < 2; ++qt)
#pragma unroll
    for (int ks = 0; ks < 2; ++ks)
      fB[qt][ks] = *(const f16x8*)(fq + (size_t)(b * 4096 + q0 + qt * 16 + l15) * 64 + ks * 32 + l4 * 8);

  f32x4 oacc[2][4];
#pragma unroll
  for (int qt = 0; qt < 2; ++qt)
#pragma unroll
    for (int ct = 0; ct < 4; ++ct) oacc[qt][ct] = (f32x4)(0.f);
  float lrun[2] = {0.f, 0.f};

  // ---- prologue: S(0), prefetch gA(1), hb(0), write P(0) ----
  f16x8 gAn[2];
  gAn[0] = *(const f16x8*)(gkb);
  gAn[1] = *(const f16x8*)(gkb + 32);
  f32x4 sacc[2];
#pragma unroll
  for (int qt = 0; qt < 2; ++qt) sacc[qt] = (f32x4)(0.f);
#pragma unroll
  for (int ks = 0; ks < 2; ++ks)
#pragma unroll
    for (int qt = 0; qt < 2; ++qt) sacc[qt] = MFMA16F(gAn[ks], fB[qt][ks], sacc[qt]);
  gAn[0] = *(const f16x8*)(gkb + (size_t)64 * 64);
  gAn[1] = *(const f16x8*)(gkb + (size_t)64 * 64 + 32);
  f16x8 hbv[2][4];
#pragma unroll
  for (int ks = 0; ks < 2; ++ks)
#pragma unroll
    for (int ct = 0; ct < 4; ++ct)
      hbv[ks][ct] = *(const f16x8*)(htw + (size_t)(ct * 16) * 4096 + ks * 32);
  {
    u16* pbuf = lds_p[0];
#pragma unroll
    for (int qt = 0; qt < 2; ++qt) {
      f32x4 p;
#pragma unroll
      for (int r = 0; r < 4; ++r) p[r] = __builtin_amdgcn_exp2f(sacc[qt][r] - 12.0f);
      lrun[qt] += (p[0] + p[1]) + (p[2] + p[3]);
      u32x2 pkd; pkd[0] = pk2(p[0], p[1]); pkd[1] = pk2(p[2], p[3]);
      int row = qt * 16 + l15, keyb = w * 16 + (l4 << 2);
      *(u32x2*)(pbuf + row * 64 + (((keyb >> 3) ^ (row & 7)) << 3) + (keyb & 7)) = pkd;
    }
  }
  __syncthreads();

  // ---- main loop: iters 0..62 (PV(63) peeled) ----
  for (int kt = 0; kt < 63; ++kt) {
    // S(kt+1): gAn loaded an iter ago
    f32x4 sn[2];
#pragma unroll
    for (int qt = 0; qt < 2; ++qt) sn[qt] = (f32x4)(0.f);
#pragma unroll
    for (int ks = 0; ks < 2; ++ks)
#pragma unroll
      for (int qt = 0; qt < 2; ++qt) sn[qt] = MFMA16F(gAn[ks], fB[qt][ks], sn[qt]);
    // PV(kt): P from LDS buf[kt&1], hb from regs (loaded last iter)
    const u16* pbuf = lds_p[kt & 1];
#pragma unroll
    for (int ks = 0; ks < 2; ++ks) {
      f16x8 pf[2];
#pragma unroll
      for (int qt = 0; qt < 2; ++qt) pf[qt] = ldsFrag(pbuf, qt * 16 + l15, ks * 4 + l4);
#pragma unroll
      for (int qt = 0; qt < 2; ++qt)
#pragma unroll
        for (int ct = 0; ct < 4; ++ct)
          oacc[qt][ct] = MFMA16F(pf[qt], hbv[ks][ct], oacc[qt][ct]);
    }
    // prefetch gA(kt+2), hb(kt+1); completed by barrier drain
    if (kt < 62) {
      gAn[0] = *(const f16x8*)(gkb + (size_t)(kt + 2) * 64 * 64);
      gAn[1] = *(const f16x8*)(gkb + (size_t)(kt + 2) * 64 * 64 + 32);
    }
    const size_t hoff = (size_t)(kt + 1) * 64;
#pragma unroll
    for (int ks = 0; ks < 2; ++ks)
#pragma unroll
      for (int ct = 0; ct < 4; ++ct)
        hbv[ks][ct] = *(const f16x8*)(htw + (size_t)(ct * 16) * 4096 + hoff + ks * 32);
    // exp(kt+1) + P-write
    u16* wbuf = lds_p[(kt + 1) & 1];
#pragma unroll
    for (int qt = 0; qt < 2; ++qt) {
      f32x4 p;
#pragma unroll
      for (int r = 0; r < 4; ++r) p[r] = __builtin_amdgcn_exp2f(sn[qt][r] - 12.0f);
      lrun[qt] += (p[0] + p[1]) + (p[2] + p[3]);
      u32x2 pkd; pkd[0] = pk2(p[0], p[1]); pkd[1] = pk2(p[2], p[3]);
      int row = qt * 16 + l15, keyb = w * 16 + (l4 << 2);
      *(u32x2*)(wbuf + row * 64 + (((keyb >> 3) ^ (row & 7)) << 3) + (keyb & 7)) = pkd;
    }
    __syncthreads();
  }
  // ---- tail: PV(63) ----
  {
    const u16* pbuf = lds_p[1];
#pragma unroll
    for (int ks = 0; ks < 2; ++ks) {
      f16x8 pf[2];
#pragma unroll
      for (int qt = 0; qt < 2; ++qt) pf[qt] = ldsFrag(pbuf, qt * 16 + l15, ks * 4 + l4);
#pragma unroll
      for (int qt = 0; qt < 2; ++qt)
#pragma unroll
        for (int ct = 0; ct < 4; ++ct)
          oacc[qt][ct] = MFMA16F(pf[qt], hbv[ks][ct], oacc[qt][ct]);
    }
  }

  // ---- row-sum reduction across l4-groups and waves ----
#pragma unroll
  for (int qt = 0; qt < 2; ++qt) {
    lrun[qt] += __shfl_xor(lrun[qt], 16);
    lrun[qt] += __shfl_xor(lrun[qt], 32);
  }
  if (l4 == 0) {
#pragma unroll
    for (int qt = 0; qt < 2; ++qt) lds_red[w * 32 + qt * 16 + l15] = lrun[qt];
  }
  __syncthreads();
  if (t < 32) {
    float s = (lds_red[t] + lds_red[32 + t]) + (lds_red[64 + t] + lds_red[96 + t]);
    lds_linv[t] = gamma / s;                   // fold gamma into 1/l
  }
  __syncthreads();

  // ---- epilogue: out = x + O * (gamma/l) ----
#pragma unroll
  for (int qt = 0; qt < 2; ++qt) {
    f32x4 linv = *(const f32x4*)&lds_linv[qt * 16 + (l4 << 2)];
#pragma unroll
    for (int ct = 0; ct < 4; ++ct) {
      int c = vc0 + w * 64 + ct * 16 + l15;
#pragma unroll
      for (int r = 0; r < 4; ++r) {
        int q = q0 + qt * 16 + (l4 << 2) + r;
        size_t idx = ((size_t)(b * 4096 + q) << 9) + c;
        out[idx] = x[idx] + oacc[qt][ct][r] * linv[r];
      }
    }
  }
}

extern "C" void kernel_launch(void* const* d_in, const int* in_sizes, int n_in,
                              void* d_out, int out_size, void* d_ws, size_t ws_size,
                              hipStream_t stream) {
  const float* x   = (const float*)d_in[0];
  const float* Wf  = (const float*)d_in[1];
  const float* bfv = (const float*)d_in[2];
  const float* Wg  = (const float*)d_in[3];
  const float* bgv = (const float*)d_in[4];
  const float* Wh  = (const float*)d_in[5];
  const float* bhv = (const float*)d_in[6];
  const float* gam = (const float*)d_in[7];
  float* out = (float*)d_out;

  char* ws = (char*)d_ws;                  // total scratch: ~21.6 MB
  u16*   Wt    = (u16*)(ws);               // 640*512*2   = 655360
  float* biasc = (float*)(ws + 655360);    // 640*4       = 2560
  u16*   fo    = (u16*)(ws + 657920);      // 16384*64*2  = 2097152
  u16*   go    = (u16*)(ws + 2755072);     // 2097152
  u16*   ht    = (u16*)(ws + 4852224);     // 4*512*4096*2 = 16777216

  pack_weights2<<<80, 256, 0, stream>>>(Wf, Wg, Wh, bfv, bgv, bhv, Wt, biasc);
  proj_gemm4<<<256, 512, 0, stream>>>(x, Wt, biasc, fo, go, ht);
  attn7<<<1024, 256, 0, stream>>>((const f16*)fo, (const f16*)go, (const f16*)ht, x, gam, out);
}